// Round 2
// baseline (435.354 us; speedup 1.0000x reference)
//
#include <hip/hip_runtime.h>

#define IN_DIM 300
#define MEM    150
#define GW     640   // 4 gates interleaved: col = 4*j + g, j in [0,160)
#define KX     300   // x-proj real K
#define KXP    320   // x-proj padded K (bf16 A buffer pitch)
#define KH     160   // level GEMM K (padded, H buffer is pre-padded)
#define NLEAF  65536
#define NTOT   87381
#define DEPTH  9

static const int SIZES[DEPTH] = {65536,16384,4096,1024,256,64,16,4,1};
static const int OFF[DEPTH]   = {0,65536,81920,86016,87040,87296,87360,87376,87380};

typedef __attribute__((ext_vector_type(8))) short short8;
typedef __attribute__((ext_vector_type(4))) float f32x4;

__device__ __forceinline__ float sigf(float x) { return 1.0f / (1.0f + __expf(-x)); }
__device__ __forceinline__ float tanhf_fast(float x) {
    float e = __expf(2.0f * x);
    return 1.0f - 2.0f / (e + 1.0f);
}
__device__ __forceinline__ unsigned short f2bf(float f) {
    union { float f; unsigned u; } v; v.f = f;
    unsigned r = v.u + 0x7FFF + ((v.u >> 16) & 1);
    return (unsigned short)(r >> 16);
}
__device__ __forceinline__ float bf2f(unsigned short u) {
    union { unsigned u; float f; } v; v.u = ((unsigned)u) << 16; return v.f;
}

// async global->LDS, 16 bytes per lane
typedef const __attribute__((address_space(1))) unsigned int* as1_u32p;
typedef __attribute__((address_space(3))) unsigned int* as3_u32p;
__device__ __forceinline__ void gl_lds16(const unsigned short* g, unsigned short* l) {
    __builtin_amdgcn_global_load_lds((as1_u32p)g, (as3_u32p)l, 16, 0, 0);
}

// ---------------- weight packing --------------------------------------------
// W4xT: 640 x KXP, row c=4j+g (gate-interleaved), from W_gx[k][j]
// W4hT: 640 x KH  (same layout, for combined small levels)
// WfhT: 256 x KH  (f-gate only, row c=j)
// W3hT: 512 x KH  (row c=3j+g, g in {i,u,o}), bias b3h includes b_{i,u,o}h
__global__ void pack_weights(const float* __restrict__ Wix, const float* __restrict__ Wfx,
                             const float* __restrict__ Wux, const float* __restrict__ Wox,
                             const float* __restrict__ bix, const float* __restrict__ bfx,
                             const float* __restrict__ bux, const float* __restrict__ box,
                             const float* __restrict__ Wih, const float* __restrict__ Wfh,
                             const float* __restrict__ Wuh, const float* __restrict__ Woh,
                             const float* __restrict__ bih, const float* __restrict__ bfh,
                             const float* __restrict__ buh, const float* __restrict__ boh,
                             unsigned short* __restrict__ W4xT, unsigned short* __restrict__ W4hT,
                             unsigned short* __restrict__ WfhT, unsigned short* __restrict__ W3hT,
                             float* __restrict__ b4x, float* __restrict__ b4hf,
                             float* __restrict__ bfhb, float* __restrict__ b3h)
{
    int stride = gridDim.x * blockDim.x;
    int tid = blockIdx.x * blockDim.x + threadIdx.x;
    for (int idx = tid; idx < GW * KXP; idx += stride) {
        int c = idx / KXP, k = idx - c * KXP;
        int j = c >> 2, g = c & 3;
        const float* W = (g == 0) ? Wix : (g == 1) ? Wfx : (g == 2) ? Wux : Wox;
        W4xT[idx] = (j < MEM && k < KX) ? f2bf(W[k * MEM + j]) : (unsigned short)0;
    }
    for (int idx = tid; idx < GW * KH; idx += stride) {
        int c = idx / KH, k = idx - c * KH;
        int j = c >> 2, g = c & 3;
        const float* W = (g == 0) ? Wih : (g == 1) ? Wfh : (g == 2) ? Wuh : Woh;
        W4hT[idx] = (j < MEM && k < MEM) ? f2bf(W[k * MEM + j]) : (unsigned short)0;
    }
    for (int idx = tid; idx < 256 * KH; idx += stride) {
        int c = idx / KH, k = idx - c * KH;
        WfhT[idx] = (c < MEM && k < MEM) ? f2bf(Wfh[k * MEM + c]) : (unsigned short)0;
    }
    for (int idx = tid; idx < 512 * KH; idx += stride) {
        int c = idx / KH, k = idx - c * KH;
        int j = c / 3, g = c - 3 * j;
        const float* W = (g == 0) ? Wih : (g == 1) ? Wuh : Woh;
        W3hT[idx] = (c < 480 && j < MEM && k < MEM) ? f2bf(W[k * MEM + j]) : (unsigned short)0;
    }
    for (int idx = tid; idx < GW; idx += stride) {
        int j = idx >> 2, g = idx & 3;
        const float* b = (g == 0) ? bix : (g == 1) ? bfx : (g == 2) ? bux : box;
        b4x[idx]  = (j < MEM) ? b[j] : 0.0f;
        b4hf[idx] = (g == 1 && j < MEM) ? bfh[j] : 0.0f;
    }
    for (int idx = tid; idx < 256; idx += stride)
        bfhb[idx] = (idx < MEM) ? bfh[idx] : 0.0f;
    for (int idx = tid; idx < 512; idx += stride) {
        int j = idx / 3, g = idx - 3 * j;
        const float* b = (g == 0) ? bih : (g == 1) ? buh : boh;
        b3h[idx] = (idx < 480 && j < MEM) ? b[j] : 0.0f;
    }
}

// ---------------- embs fp32 -> bf16, padded to KXP cols ------------------------
__global__ void conv_embs(const float* __restrict__ embs, unsigned short* __restrict__ Abf)
{
    int idx = blockIdx.x * 256 + threadIdx.x;
    if (idx >= NTOT * (KXP / 8)) return;
    int n = idx / (KXP / 8), c = idx - n * (KXP / 8);
    int c0 = c * 8;
    unsigned short v[8];
    if (c0 + 8 <= KX) {
        const float4* p = (const float4*)(embs + (size_t)n * KX + c0);
        float4 f0 = p[0], f1 = p[1];
        v[0]=f2bf(f0.x); v[1]=f2bf(f0.y); v[2]=f2bf(f0.z); v[3]=f2bf(f0.w);
        v[4]=f2bf(f1.x); v[5]=f2bf(f1.y); v[6]=f2bf(f1.z); v[7]=f2bf(f1.w);
    } else {
        const float* row = embs + (size_t)n * KX;
        #pragma unroll
        for (int j = 0; j < 8; ++j) {
            int col = c0 + j;
            v[j] = (col < KX) ? f2bf(row[col]) : (unsigned short)0;
        }
    }
    *(short8*)&Abf[(size_t)n * KXP + c0] = *(short8*)v;
}

// ---------------- bf16 MFMA GEMM with global_load_lds staging ------------------
// C[M x N] = A[M x KPAD] @ BT^T + bias. Tile 128x128, BK=32, double-buffered,
// one barrier per K-step. Epilogue goes through a 32KB LDS transpose tile
// (reusing staging LDS): leaf blocks (FUSE && m0<NLEAF, gate-interleaved cols)
// compute the LSTM cell in-kernel and write out/C/Hbf directly; other blocks
// write bf16 rows with guard col<nValid.
template<int KPAD, bool FUSE>
__global__ __launch_bounds__(256) void gemm_lds(
    const unsigned short* __restrict__ A, int M,
    const unsigned short* __restrict__ BT,
    const float* __restrict__ bias,
    unsigned short* __restrict__ Cout, int pitch, int nValid, int ntl,
    const float* __restrict__ bih, const float* __restrict__ buh,
    const float* __restrict__ boh,
    float* __restrict__ outLeaf, float* __restrict__ CLeaf,
    unsigned short* __restrict__ HbfLeaf)
{
    __shared__ __align__(16) unsigned short lds[16384];   // As[2]|Bs[2] / epi tile

    // bijective XCD swizzle (m204)
    const int nwg = gridDim.x;
    const int orig = blockIdx.x;
    const int qq = nwg >> 3, rr = nwg & 7;
    const int xcd = orig & 7, lin = orig >> 3;
    const int dd = (xcd < rr ? xcd * (qq + 1) : rr * (qq + 1) + (xcd - rr) * qq) + lin;
    const int mtile = dd / ntl, ntile = dd - mtile * ntl;

    const int t = threadIdx.x;
    const int m0 = mtile * 128, n0 = ntile * 128;
    const int l = t & 63, w = t >> 6;
    const int l15 = l & 15, q = l >> 4;
    const int wm = (w & 1) * 64, wn = (w >> 1) * 64;

    // staging: thread t covers LDS 16B chunk t*8 (rows 0..63) and +2048 (rows
    // 64..127). row = t>>2, k-chunk = t&3, source k-chunk XOR (row&3).
    const int srow = t >> 2;
    const int scol = ((t & 3) ^ (srow & 3)) * 8;
    int gr0 = m0 + srow;      if (gr0 >= M) gr0 = M - 1;
    int gr1 = m0 + 64 + srow; if (gr1 >= M) gr1 = M - 1;
    const unsigned short* a0 = A + (size_t)gr0 * KPAD + scol;
    const unsigned short* a1 = A + (size_t)gr1 * KPAD + scol;
    const unsigned short* b0 = BT + (size_t)(n0 + srow) * KPAD + scol;
    const unsigned short* b1 = BT + (size_t)(n0 + 64 + srow) * KPAD + scol;

    f32x4 acc[4][4];
    #pragma unroll
    for (int i = 0; i < 4; ++i)
        #pragma unroll
        for (int j = 0; j < 4; ++j)
            acc[i][j] = (f32x4){0.f, 0.f, 0.f, 0.f};

    const int kiters = KPAD >> 5;
    unsigned short* As = lds;          // [2][4096]
    unsigned short* Bs = lds + 8192;   // [2][4096]
    gl_lds16(a0, As + t * 8);
    gl_lds16(a1, As + 2048 + t * 8);
    gl_lds16(b0, Bs + t * 8);
    gl_lds16(b1, Bs + 2048 + t * 8);
    __syncthreads();

    int cur = 0;
    for (int kt = 0; kt < kiters; ++kt) {
        if (kt + 1 < kiters) {
            const int ko = (kt + 1) << 5;
            const int nb = cur ^ 1;
            gl_lds16(a0 + ko, As + nb * 4096 + t * 8);
            gl_lds16(a1 + ko, As + nb * 4096 + 2048 + t * 8);
            gl_lds16(b0 + ko, Bs + nb * 4096 + t * 8);
            gl_lds16(b1 + ko, Bs + nb * 4096 + 2048 + t * 8);
        }
        short8 a[4], b[4];
        const int csw = (q ^ (l15 & 3)) * 8;
        #pragma unroll
        for (int i = 0; i < 4; ++i)
            a[i] = *(const short8*)&As[cur * 4096 + (wm + i * 16 + l15) * 32 + csw];
        #pragma unroll
        for (int j = 0; j < 4; ++j)
            b[j] = *(const short8*)&Bs[cur * 4096 + (wn + j * 16 + l15) * 32 + csw];
        #pragma unroll
        for (int i = 0; i < 4; ++i)
            #pragma unroll
            for (int j = 0; j < 4; ++j)
                acc[i][j] = __builtin_amdgcn_mfma_f32_16x16x32_bf16(a[i], b[j], acc[i][j], 0, 0, 0);
        __syncthreads();
        cur ^= 1;
    }

    // ---- epilogue: bias + bf16 into LDS tile [128][128] ----
    float bj[4];
    #pragma unroll
    for (int j = 0; j < 4; ++j) bj[j] = bias[n0 + wn + j * 16 + l15];
    #pragma unroll
    for (int i = 0; i < 4; ++i)
        #pragma unroll
        for (int j = 0; j < 4; ++j)
            #pragma unroll
            for (int r = 0; r < 4; ++r)
                lds[(wm + i * 16 + q * 4 + r) * 128 + wn + j * 16 + l15] =
                    f2bf(acc[i][j][r] + bj[j]);
    __syncthreads();

    if (FUSE && m0 < NLEAF) {
        // leaf LSTM cell: tile holds cols 4*j+g for j in [32*ntile, 32*ntile+32)
        #pragma unroll
        for (int s = 0; s < 16; ++s) {
            int idx = (s << 8) + t;
            int row = idx >> 5, jl = idx & 31;
            int grow = m0 + row;                  // < NLEAF <= M always
            int j = ntile * 32 + jl;
            const unsigned short* g4 = &lds[row * 128 + jl * 4];
            if (j < MEM) {
                float gi = bf2f(g4[0]) + bih[j];
                float gu = bf2f(g4[2]) + buh[j];
                float go = bf2f(g4[3]) + boh[j];
                float iv = sigf(gi), uv = tanhf_fast(gu), ov = sigf(go);
                float c = iv * uv;
                float h = ov * tanhf_fast(c);
                outLeaf[(size_t)grow * MEM + j] = h;
                CLeaf[(size_t)grow * MEM + j] = c;
                HbfLeaf[(size_t)grow * KH + j] = f2bf(h);
            } else if (j < KH) {
                HbfLeaf[(size_t)grow * KH + j] = 0;
            }
        }
    } else {
        int row = t >> 1, half = t & 1;
        int grow = m0 + row;
        if (grow < M) {
            const unsigned short* src = &lds[row * 128 + half * 64];
            unsigned short* dst = Cout + (size_t)grow * pitch + n0 + half * 64;
            #pragma unroll
            for (int c8 = 0; c8 < 8; ++c8) {
                int col0 = n0 + half * 64 + c8 * 8;
                if (col0 < nValid)
                    *(short8*)(dst + c8 * 8) = *(const short8*)(src + c8 * 8);
            }
        }
    }
}

// ---------------- hsum: parent h-sum in bf16 (pads stay zero) ------------------
__global__ void hsum_k(const unsigned short* __restrict__ Hprev,
                       unsigned short* __restrict__ HS, int n)
{
    int idx = blockIdx.x * 256 + threadIdx.x;
    if (idx >= n * (KH / 8)) return;
    int nn = idx / (KH / 8), c8 = idx - nn * (KH / 8);
    const unsigned short* b = Hprev + (size_t)(4 * nn) * KH + c8 * 8;
    short8 v0 = *(const short8*)(b);
    short8 v1 = *(const short8*)(b + KH);
    short8 v2 = *(const short8*)(b + 2 * KH);
    short8 v3 = *(const short8*)(b + 3 * KH);
    unsigned short o[8];
    #pragma unroll
    for (int e = 0; e < 8; ++e) {
        float s = bf2f((unsigned short)v0[e]) + bf2f((unsigned short)v1[e])
                + bf2f((unsigned short)v2[e]) + bf2f((unsigned short)v3[e]);
        o[e] = f2bf(s);
    }
    *(short8*)(HS + (size_t)nn * KH + c8 * 8) = *(short8*)o;
}

// ---------------- split-path combine (big levels) ------------------------------
// Gf: per-child f pre-act (pitch 160, bias bfh included)
// G3: hsum@{W_ih,W_uh,W_oh} at col 3m+g (pitch 512, biases included)
// P : x-proj rows (gate-interleaved, pitch GW, b4x included)
__global__ void level_ew_split(const unsigned short* __restrict__ Gf,
                               const unsigned short* __restrict__ G3,
                               const unsigned short* __restrict__ P,
                               const float* __restrict__ Cprev,
                               float* __restrict__ outRow, float* __restrict__ Crow,
                               unsigned short* __restrict__ HbfRow, int n)
{
    int idx = blockIdx.x * 256 + threadIdx.x;
    if (idx >= n * MEM) return;
    int nn = idx / MEM, m = idx - nn * MEM;
    const unsigned short* xr = P + (size_t)nn * GW + 4 * m;
    float xi = bf2f(xr[0]), xf = bf2f(xr[1]), xu = bf2f(xr[2]), xo = bf2f(xr[3]);
    const unsigned short* g3 = G3 + (size_t)nn * 512 + 3 * m;
    float iv = sigf(xi + bf2f(g3[0]));
    float uv = tanhf_fast(xu + bf2f(g3[1]));
    float ov = sigf(xo + bf2f(g3[2]));
    float fc = 0.0f;
    #pragma unroll
    for (int k = 0; k < 4; ++k) {
        float f = sigf(xf + bf2f(Gf[(size_t)(4 * nn + k) * 160 + m]));
        fc += f * Cprev[(4 * nn + k) * MEM + m];
    }
    float c = iv * uv + fc;
    float h = ov * tanhf_fast(c);
    outRow[idx] = h;
    Crow[idx] = c;
    HbfRow[(size_t)nn * KH + m] = f2bf(h);
    if (m < KH - MEM) HbfRow[(size_t)nn * KH + MEM + m] = 0;
}

// ---------------- combined-path combine (small levels) -------------------------
__global__ void level_ew_comb(const unsigned short* __restrict__ G,
                              const unsigned short* __restrict__ P,
                              const float* __restrict__ Cprev,
                              const float* __restrict__ bih, const float* __restrict__ buh,
                              const float* __restrict__ boh,
                              float* __restrict__ outRow, float* __restrict__ Crow,
                              unsigned short* __restrict__ HbfRow, int n)
{
    int idx = blockIdx.x * 256 + threadIdx.x;
    if (idx >= n * MEM) return;
    int nn = idx / MEM, m = idx - nn * MEM;
    const unsigned short* xr = P + (size_t)nn * GW + 4 * m;
    float ip = bf2f(xr[0]) + bih[m];
    float fx = bf2f(xr[1]);
    float up = bf2f(xr[2]) + buh[m];
    float op = bf2f(xr[3]) + boh[m];
    float fc = 0.0f;
    #pragma unroll
    for (int k = 0; k < 4; ++k) {
        const unsigned short* gr = G + (size_t)(4 * nn + k) * GW + 4 * m;
        ip += bf2f(gr[0]);
        up += bf2f(gr[2]);
        op += bf2f(gr[3]);
        float f = sigf(fx + bf2f(gr[1]));
        fc += f * Cprev[(4 * nn + k) * MEM + m];
    }
    float i = sigf(ip), u = tanhf_fast(up), o = sigf(op);
    float c = i * u + fc;
    float h = o * tanhf_fast(c);
    outRow[idx] = h;
    Crow[idx] = c;
    HbfRow[(size_t)nn * KH + m] = f2bf(h);
    if (m < KH - MEM) HbfRow[(size_t)nn * KH + MEM + m] = 0;
}

extern "C" void kernel_launch(void* const* d_in, const int* in_sizes, int n_in,
                              void* d_out, int out_size, void* d_ws, size_t ws_size,
                              hipStream_t stream)
{
    (void)in_sizes; (void)n_in; (void)out_size;
    const float* embs = (const float*)d_in[0];
    const float* Wix = (const float*)d_in[1];  const float* bix = (const float*)d_in[2];
    const float* Wfx = (const float*)d_in[3];  const float* bfx = (const float*)d_in[4];
    const float* Wux = (const float*)d_in[5];  const float* bux = (const float*)d_in[6];
    const float* Wox = (const float*)d_in[7];  const float* box = (const float*)d_in[8];
    const float* Wih = (const float*)d_in[9];  const float* bih = (const float*)d_in[10];
    const float* Wfh = (const float*)d_in[11]; const float* bfh = (const float*)d_in[12];
    const float* Wuh = (const float*)d_in[13]; const float* buh = (const float*)d_in[14];
    const float* Woh = (const float*)d_in[15]; const float* boh = (const float*)d_in[16];
    float* out = (float*)d_out;

    char* p = (char*)d_ws;
    auto alloc = [&](size_t bytes) -> char* {
        char* r = p;
        p += (bytes + 255) & ~(size_t)255;
        return r;
    };
    unsigned short* PG   = (unsigned short*)alloc((size_t)NTOT * GW * 2);   // 111.8 MB
    float*          C    = (float*)alloc((size_t)NTOT * MEM * 4);           //  52.4 MB
    unsigned short* Hbf  = (unsigned short*)alloc((size_t)NTOT * KH * 2);   //  28.0 MB
    unsigned short* W4xT = (unsigned short*)alloc((size_t)GW * KXP * 2);
    unsigned short* W4hT = (unsigned short*)alloc((size_t)GW * KH * 2);
    unsigned short* WfhT = (unsigned short*)alloc((size_t)256 * KH * 2);
    unsigned short* W3hT = (unsigned short*)alloc((size_t)512 * KH * 2);
    float*          b4x  = (float*)alloc(GW * 4);
    float*          b4hf = (float*)alloc(GW * 4);
    float*          bfhb = (float*)alloc(256 * 4);
    float*          b3h  = (float*)alloc(512 * 4);
    if ((size_t)(p - (char*)d_ws) > ws_size) return;

    // Scratch aliased into PG's leaf region (bytes [0, 84MB)): x-proj never
    // writes PG rows < NLEAF (leaf blocks write out/C/Hbf directly), and its
    // A-reads (Abf, 55.9 MB) sit entirely below the internal PG rows (84MB+).
    unsigned short* Abf = PG;                                        // NTOT*KXP
    unsigned short* Gf  = PG;                                        // <= 21 MB
    unsigned short* G3  = PG + (size_t)65536 * 160;                  // <= 16.8 MB
    unsigned short* HS  = PG + (size_t)65536 * 160 + (size_t)16384 * 512;
    unsigned short* Gc  = PG;                                        // <= 327 KB

    pack_weights<<<128, 256, 0, stream>>>(Wix, Wfx, Wux, Wox, bix, bfx, bux, box,
                                          Wih, Wfh, Wuh, Woh, bih, bfh, buh, boh,
                                          W4xT, W4hT, WfhT, W3hT, b4x, b4hf, bfhb, b3h);

    conv_embs<<<(NTOT * (KXP / 8) + 255) / 256, 256, 0, stream>>>(embs, Abf);

    // x-projections for ALL nodes; leaf rows fused to out/C/Hbf in-epilogue
    {
        int mt = (NTOT + 127) / 128;
        gemm_lds<KXP, true><<<mt * 5, 256, 0, stream>>>(
            Abf, NTOT, W4xT, b4x, PG, GW, GW, 5, bih, buh, boh, out, C, Hbf);
    }

    for (int d = 1; d < DEPTH; ++d) {
        int nprev = SIZES[d - 1];
        int n = SIZES[d];
        const unsigned short* Hprev = Hbf + (size_t)OFF[d - 1] * KH;
        if (nprev >= 4096) {
            // split path: f per-child + iuo on hsum
            hsum_k<<<(n * (KH / 8) + 255) / 256, 256, 0, stream>>>(Hprev, HS, n);
            int mtf = (nprev + 127) / 128;
            gemm_lds<KH, false><<<mtf * 2, 256, 0, stream>>>(
                Hprev, nprev, WfhT, bfhb, Gf, 160, 160, 2,
                nullptr, nullptr, nullptr, nullptr, nullptr, nullptr);
            int mt3 = (n + 127) / 128;
            gemm_lds<KH, false><<<mt3 * 4, 256, 0, stream>>>(
                HS, n, W3hT, b3h, G3, 512, 480, 4,
                nullptr, nullptr, nullptr, nullptr, nullptr, nullptr);
            level_ew_split<<<(n * MEM + 255) / 256, 256, 0, stream>>>(
                Gf, G3, PG + (size_t)OFF[d] * GW, C + (size_t)OFF[d - 1] * MEM,
                out + (size_t)OFF[d] * MEM, C + (size_t)OFF[d] * MEM,
                Hbf + (size_t)OFF[d] * KH, n);
        } else {
            // combined path (small levels): one 4-gate GEMM + combine
            int mt = (nprev + 127) / 128;
            gemm_lds<KH, false><<<mt * 5, 256, 0, stream>>>(
                Hprev, nprev, W4hT, b4hf, Gc, GW, GW, 5,
                nullptr, nullptr, nullptr, nullptr, nullptr, nullptr);
            level_ew_comb<<<(n * MEM + 255) / 256, 256, 0, stream>>>(
                Gc, PG + (size_t)OFF[d] * GW, C + (size_t)OFF[d - 1] * MEM,
                bih, buh, boh,
                out + (size_t)OFF[d] * MEM, C + (size_t)OFF[d] * MEM,
                Hbf + (size_t)OFF[d] * KH, n);
        }
    }
}